// Round 4
// baseline (540.150 us; speedup 1.0000x reference)
//
#include <hip/hip_runtime.h>

#define N_   16
#define C_   512
#define GRP  4
#define CG   128
#define MIP  16

__device__ __forceinline__ float bf_lo(unsigned u) { return __uint_as_float(u << 16); }
__device__ __forceinline__ float bf_hi(unsigned u) { return __uint_as_float(u & 0xFFFF0000u); }
__device__ __forceinline__ float bf1(unsigned short s) { return __uint_as_float((unsigned)s << 16); }

__device__ __forceinline__ float ld_scalar(const void* p, int i, bool isbf) {
    return isbf ? bf1(((const unsigned short*)p)[i]) : ((const float*)p)[i];
}

// Per-block dtype sniff on x[0..255] words (same 1 KB for every block, L2-hot).
__device__ __forceinline__ bool sniff_isbf(const unsigned* __restrict__ x32,
                                           int t, unsigned* s_flag) {
    if (t < 64) {
        int cnt = 0;
        #pragma unroll
        for (int k = 0; k < 4; ++k) {
            unsigned w = x32[t + 64 * k];
            unsigned e = (w >> 7) & 0xFFu;
            cnt += (e >= 0x60u && e <= 0x9Fu) ? 1 : 0;
        }
        #pragma unroll
        for (int off = 32; off > 0; off >>= 1) cnt += __shfl_down(cnt, off, 64);
        if (t == 0) *s_flag = (cnt >= 192) ? 1u : 0u;
    }
    __syncthreads();
    return *s_flag != 0u;
}

// ---------------------------------------------------------------------------
// K1: per-(n,ch) 64x64 tile -> row means (gh) and col means (gw).
// grid = 8192 blocks, 256 threads.  (byte-identical to round 2)
// ---------------------------------------------------------------------------
__global__ __launch_bounds__(256) void kreduce(const void* __restrict__ xv,
                                               float* __restrict__ gh,
                                               float* __restrict__ gw) {
    __shared__ float scratch[32][65];
    __shared__ unsigned flag_s;
    const int bid = blockIdx.x;            // n*512 + ch
    const int t = threadIdx.x;
    const bool isbf = sniff_isbf((const unsigned*)xv, t, &flag_s);

    if (isbf) {
        const uint4* src = (const uint4*)((const unsigned short*)xv + (size_t)bid * 4096);
        float cp[8] = {0,0,0,0,0,0,0,0};
        #pragma unroll
        for (int hf = 0; hf < 2; ++hf) {
            int idx = t + hf * 256;        // 8 bf16 per uint4; 8 uint4 per row
            int r = idx >> 3;
            uint4 v = src[idx];
            unsigned uu[4] = {v.x, v.y, v.z, v.w};
            float rp = 0.f;
            #pragma unroll
            for (int k = 0; k < 4; ++k) {
                float f0 = bf_lo(uu[k]), f1 = bf_hi(uu[k]);
                rp += f0 + f1;
                cp[2*k] += f0; cp[2*k+1] += f1;
            }
            rp += __shfl_xor(rp, 1);       // 8 lanes share a row
            rp += __shfl_xor(rp, 2);
            rp += __shfl_xor(rp, 4);
            if ((t & 7) == 0) gh[(size_t)bid * 64 + r] = rp * (1.f/64.f);
        }
        #pragma unroll
        for (int k = 0; k < 8; ++k) scratch[t >> 3][(t & 7) * 8 + k] = cp[k];
    } else {
        const float4* src = (const float4*)((const float*)xv + (size_t)bid * 4096);
        float cp[4] = {0,0,0,0};
        #pragma unroll
        for (int it = 0; it < 4; ++it) {
            int idx = t + it * 256;        // 4 fp32 per float4; 16 per row
            int r = idx >> 4;
            float4 v = src[idx];
            float rp = (v.x + v.y) + (v.z + v.w);
            cp[0] += v.x; cp[1] += v.y; cp[2] += v.z; cp[3] += v.w;
            rp += __shfl_xor(rp, 1);       // 16 lanes share a row
            rp += __shfl_xor(rp, 2);
            rp += __shfl_xor(rp, 4);
            rp += __shfl_xor(rp, 8);
            if ((t & 15) == 0) gh[(size_t)bid * 64 + r] = rp * (1.f/64.f);
        }
        #pragma unroll
        for (int k = 0; k < 4; ++k) scratch[t >> 4][(t & 15) * 4 + k] = cp[k];
    }
    __syncthreads();
    if (t < 64) {                          // final col reduce -> gw
        const int nr = isbf ? 32 : 16;
        float s = 0.f;
        for (int i = 0; i < nr; ++i) s += scratch[i][t];
        gw[(size_t)bid * 64 + t] = s * (1.f/64.f);
    }
}

// ---------------------------------------------------------------------------
// K2: per (n,g): y = hswish(BN(W1@[gh|gw]+b1)) in LDS, then full attention
// maps A_h/A_w -> global.  grid = 64 blocks.  (byte-identical to round 2)
// ---------------------------------------------------------------------------
__global__ __launch_bounds__(256) void kmid(
    const void* __restrict__ xv,
    const float* __restrict__ gh, const float* __restrict__ gw,
    const void* __restrict__ W1, const void* __restrict__ b1,
    const void* __restrict__ gamma, const void* __restrict__ beta,
    const void* __restrict__ mean, const void* __restrict__ var,
    const void* __restrict__ Wh, const void* __restrict__ bh,
    const void* __restrict__ Ww, const void* __restrict__ bw,
    float* __restrict__ aH, float* __restrict__ aW)
{
    __shared__ float W1_s[MIP * CG];       // [m][cc]
    __shared__ float Whw_s[2][CG * MIP];   // [hf][cc][m]
    __shared__ float y_s[MIP * 128];       // [m][l]
    __shared__ float bhw_s[2][CG];
    __shared__ float scale_s[MIP], shift_s[MIP], b1_s[MIP];
    __shared__ unsigned flag_s;

    const int t = threadIdx.x;
    const int ng = blockIdx.x;             // n*4 + g
    const bool isbf = sniff_isbf((const unsigned*)xv, t, &flag_s);

    // ---- stage weights ----
    if (isbf) {
        uint4 v = ((const uint4*)W1)[t];   // 2048 bf16 = 256 uint4
        unsigned uu[4] = {v.x, v.y, v.z, v.w};
        #pragma unroll
        for (int k = 0; k < 4; ++k) {
            W1_s[t*8 + 2*k]   = bf_lo(uu[k]);
            W1_s[t*8 + 2*k+1] = bf_hi(uu[k]);
        }
        uint4 a = ((const uint4*)Wh)[t];
        unsigned ua[4] = {a.x, a.y, a.z, a.w};
        #pragma unroll
        for (int k = 0; k < 4; ++k) {
            Whw_s[0][t*8 + 2*k]   = bf_lo(ua[k]);
            Whw_s[0][t*8 + 2*k+1] = bf_hi(ua[k]);
        }
        uint4 c = ((const uint4*)Ww)[t];
        unsigned uc[4] = {c.x, c.y, c.z, c.w};
        #pragma unroll
        for (int k = 0; k < 4; ++k) {
            Whw_s[1][t*8 + 2*k]   = bf_lo(uc[k]);
            Whw_s[1][t*8 + 2*k+1] = bf_hi(uc[k]);
        }
    } else {
        #pragma unroll
        for (int it = 0; it < 2; ++it) {
            int idx = t + 256 * it;        // 2048 fp32 = 512 float4
            float4 v = ((const float4*)W1)[idx];
            W1_s[idx*4] = v.x; W1_s[idx*4+1] = v.y; W1_s[idx*4+2] = v.z; W1_s[idx*4+3] = v.w;
            float4 a = ((const float4*)Wh)[idx];
            Whw_s[0][idx*4] = a.x; Whw_s[0][idx*4+1] = a.y; Whw_s[0][idx*4+2] = a.z; Whw_s[0][idx*4+3] = a.w;
            float4 c = ((const float4*)Ww)[idx];
            Whw_s[1][idx*4] = c.x; Whw_s[1][idx*4+1] = c.y; Whw_s[1][idx*4+2] = c.z; Whw_s[1][idx*4+3] = c.w;
        }
    }
    if (t < CG) bhw_s[0][t] = ld_scalar(bh, t, isbf);
    else        bhw_s[1][t - CG] = ld_scalar(bw, t - CG, isbf);
    if (t < MIP) {
        float sc = ld_scalar(gamma, t, isbf) * rsqrtf(ld_scalar(var, t, isbf) + 1e-5f);
        scale_s[t] = sc;
        shift_s[t] = ld_scalar(beta, t, isbf) - ld_scalar(mean, t, isbf) * sc;
        b1_s[t] = ld_scalar(b1, t, isbf);
    }
    __syncthreads();

    // ---- y phase: y[m][l], l = t&127, m in [half*8, half*8+8) ----
    {
        const int l = t & 127;
        const int half = t >> 7;
        const float* gbase = (l < 64) ? (gh + (size_t)ng * 8192 + l)
                                      : (gw + (size_t)ng * 8192 + (l - 64));
        float acc[8] = {0,0,0,0,0,0,0,0};
        for (int cc = 0; cc < CG; ++cc) {
            float v = gbase[(size_t)cc * 64];
            #pragma unroll
            for (int mm = 0; mm < 8; ++mm)
                acc[mm] += W1_s[(half*8 + mm) * CG + cc] * v;
        }
        #pragma unroll
        for (int mm = 0; mm < 8; ++mm) {
            int m = half*8 + mm;
            float yv = acc[mm] + b1_s[m];
            yv = yv * scale_s[m] + shift_s[m];
            float hc = fminf(fmaxf(yv + 3.f, 0.f), 6.f);
            y_s[m * 128 + l] = yv * hc * (1.f/6.f);
        }
    }
    __syncthreads();

    // ---- A phase: 16384 outputs (hf,cc,i), 64 per thread ----
    for (int k = 0; k < 64; ++k) {
        int out = t + 256 * k;             // wave-uniform (hf,cc), i = lane
        int hf = out >> 13;
        int rem = out & 8191;
        int cc = rem >> 6;
        int i = rem & 63;
        float acc = bhw_s[hf][cc];
        #pragma unroll
        for (int m = 0; m < MIP; ++m)
            acc += Whw_s[hf][cc * MIP + m] * y_s[m * 128 + hf * 64 + i];
        float s = 1.f / (1.f + __expf(-acc));
        float* dst = hf ? aW : aH;
        dst[(size_t)ng * 8192 + cc * 64 + i] = s;
    }
}

// ---------------------------------------------------------------------------
// K3: pure streaming gate: out[n,o] = x[n,p] * a_h[r] * a_w[j]
// grid = 8192 blocks, 256 threads.  (byte-identical to round 2)
// ---------------------------------------------------------------------------
__global__ __launch_bounds__(256) void kapply(const void* __restrict__ xv,
                                              const float* __restrict__ aH,
                                              const float* __restrict__ aW,
                                              void* __restrict__ outv) {
    __shared__ float ah_s[64], aw_s[64];
    __shared__ unsigned flag_s;
    const int bid = blockIdx.x;            // n*512 + o
    const int n = bid >> 9;
    const int o = bid & 511;
    const int p = (o & 127) * 4 + (o >> 7);    // channel shuffle: input channel
    const int g = p >> 7, cc = p & 127;
    const int t = threadIdx.x;
    const bool isbf = sniff_isbf((const unsigned*)xv, t, &flag_s);
    const size_t abase = (size_t)(n * 4 + g) * 8192 + (size_t)cc * 64;

    if (isbf) {
        const uint4* src = (const uint4*)((const unsigned short*)xv + ((size_t)n * 512 + p) * 4096);
        uint4 x0 = src[t];                 // issue x loads first
        uint4 x1 = src[t + 256];
        if (t < 64)       ah_s[t]      = aH[abase + t];
        else if (t < 128) aw_s[t - 64] = aW[abase + (t - 64)];
        __syncthreads();
        uint4* dst = (uint4*)((unsigned short*)outv + (size_t)bid * 4096);
        uint4 xr[2] = {x0, x1};
        #pragma unroll
        for (int hf = 0; hf < 2; ++hf) {
            int idx = t + hf * 256;
            int r = idx >> 3, j0 = (idx & 7) * 8;
            float sah = ah_s[r];
            unsigned uu[4] = {xr[hf].x, xr[hf].y, xr[hf].z, xr[hf].w};
            unsigned res[4];
            #pragma unroll
            for (int k = 0; k < 4; ++k) {
                int j = j0 + 2 * k;
                float f0 = bf_lo(uu[k]) * sah * aw_s[j];
                float f1 = bf_hi(uu[k]) * sah * aw_s[j + 1];
                unsigned u0 = __float_as_uint(f0); u0 += 0x7FFFu + ((u0 >> 16) & 1u);
                unsigned u1 = __float_as_uint(f1); u1 += 0x7FFFu + ((u1 >> 16) & 1u);
                res[k] = (u0 >> 16) | (u1 & 0xFFFF0000u);
            }
            uint4 w2; w2.x = res[0]; w2.y = res[1]; w2.z = res[2]; w2.w = res[3];
            dst[idx] = w2;
        }
    } else {
        const float4* src = (const float4*)((const float*)xv + ((size_t)n * 512 + p) * 4096);
        float4 x0 = src[t];
        float4 x1 = src[t + 256];
        float4 x2 = src[t + 512];
        float4 x3 = src[t + 768];
        if (t < 64)       ah_s[t]      = aH[abase + t];
        else if (t < 128) aw_s[t - 64] = aW[abase + (t - 64)];
        __syncthreads();
        float4* dst = (float4*)((float*)outv + (size_t)bid * 4096);
        float4 xr[4] = {x0, x1, x2, x3};
        #pragma unroll
        for (int it = 0; it < 4; ++it) {
            int idx = t + it * 256;
            int r = idx >> 4, j0 = (idx & 15) * 4;
            float sah = ah_s[r];
            float4 v = xr[it];
            v.x *= sah * aw_s[j0];
            v.y *= sah * aw_s[j0 + 1];
            v.z *= sah * aw_s[j0 + 2];
            v.w *= sah * aw_s[j0 + 3];
            dst[idx] = v;
        }
    }
}

// ---------------------------------------------------------------------------
// DIAGNOSTIC (resubmit after infra failure), asymmetric reps:
//   kreduce x5, kmid x1, kapply x5 — all idempotent, semantically a no-op.
//   R2:   f + s1 + s2 + s3          = 291.1 us
//   here: f + 5*s1 + s2 + 5*s3      = dur
//   =>  s1 + s3 = (dur - 291.1) / 4     (the optimizable streaming portion)
// H_fixed predicts dur ~ 450-550; H_kernel predicts dur > 1100.
// ---------------------------------------------------------------------------
extern "C" void kernel_launch(void* const* d_in, const int* in_sizes, int n_in,
                              void* d_out, int out_size, void* d_ws, size_t ws_size,
                              hipStream_t stream) {
    const void* x     = d_in[0];
    const void* W1    = d_in[1];
    const void* b1    = d_in[2];
    const void* gamma = d_in[3];
    const void* beta  = d_in[4];
    const void* mean  = d_in[5];
    const void* var   = d_in[6];
    const void* Wh    = d_in[7];
    const void* bh    = d_in[8];
    const void* Ww    = d_in[9];
    const void* bw    = d_in[10];

    float* ws = (float*)d_ws;
    float* gh = ws;                    // 524288 floats (2 MB)
    float* gw = gh + 524288;           // 524288 floats
    float* aH = gw + 524288;           // 524288 floats
    float* aW = aH + 524288;           // 524288 floats

    for (int rep = 0; rep < 5; ++rep)
        kreduce<<<N_ * C_, 256, 0, stream>>>(x, gh, gw);
    kmid<<<N_ * GRP, 256, 0, stream>>>(x, gh, gw, W1, b1, gamma, beta, mean, var,
                                       Wh, bh, Ww, bw, aH, aW);
    for (int rep = 0; rep < 5; ++rep)
        kapply<<<N_ * C_, 256, 0, stream>>>(x, aH, aW, d_out);
}

// Round 5
// 295.275 us; speedup vs baseline: 1.8293x; 1.8293x over previous
//
#include <hip/hip_runtime.h>

#define N_   16
#define C_   512
#define GRP  4
#define CG   128
#define MIP  16

__device__ __forceinline__ float bf_lo(unsigned u) { return __uint_as_float(u << 16); }
__device__ __forceinline__ float bf_hi(unsigned u) { return __uint_as_float(u & 0xFFFF0000u); }
__device__ __forceinline__ float bf1(unsigned short s) { return __uint_as_float((unsigned)s << 16); }

__device__ __forceinline__ float ld_scalar(const void* p, int i, bool isbf) {
    return isbf ? bf1(((const unsigned short*)p)[i]) : ((const float*)p)[i];
}

// Wave-level dtype sniff: no LDS, no barrier. Reads x[0..255] words (L2-hot).
__device__ __forceinline__ bool wave_sniff_isbf(const unsigned* __restrict__ x32,
                                                int lane) {
    int cnt = 0;
    #pragma unroll
    for (int k = 0; k < 4; ++k) {
        unsigned w = x32[lane + 64 * k];
        unsigned e = (w >> 7) & 0xFFu;
        cnt += (e >= 0x60u && e <= 0x9Fu) ? 1 : 0;
    }
    #pragma unroll
    for (int off = 32; off > 0; off >>= 1) cnt += __shfl_xor(cnt, off, 64);
    return cnt >= 192;
}

// Block-level sniff (kmid only).
__device__ __forceinline__ bool sniff_isbf(const unsigned* __restrict__ x32,
                                           int t, unsigned* s_flag) {
    if (t < 64) {
        int cnt = 0;
        #pragma unroll
        for (int k = 0; k < 4; ++k) {
            unsigned w = x32[t + 64 * k];
            unsigned e = (w >> 7) & 0xFFu;
            cnt += (e >= 0x60u && e <= 0x9Fu) ? 1 : 0;
        }
        #pragma unroll
        for (int off = 32; off > 0; off >>= 1) cnt += __shfl_down(cnt, off, 64);
        if (t == 0) *s_flag = (cnt >= 192) ? 1u : 0u;
    }
    __syncthreads();
    return *s_flag != 0u;
}

// ---------------------------------------------------------------------------
// K1: wave-autonomous tile reduce. 1024 blocks x 4 waves x 2 tiles = 8192.
// Zero LDS, zero barriers. Coalesced 1KB/instr loads; row sums close via
// 3x shfl_xor; col partials live in regs (col-block is iter-invariant per
// lane) and close via 3x shfl_xor at tile end; lanes 0..7 store float4s.
// ---------------------------------------------------------------------------
__global__ __launch_bounds__(256) void kreduce(const void* __restrict__ xv,
                                               float* __restrict__ gh,
                                               float* __restrict__ gw) {
    const int lane = threadIdx.x & 63;
    const int gwid = blockIdx.x * 4 + (threadIdx.x >> 6);   // 0..4095
    const bool isbf = wave_sniff_isbf((const unsigned*)xv, lane);

    #pragma unroll
    for (int j = 0; j < 2; ++j) {
        const int tile = gwid * 2 + j;                      // n*512 + ch
        if (isbf) {
            const uint4* src = (const uint4*)((const unsigned short*)xv + (size_t)tile * 4096);
            float cp[8] = {0,0,0,0,0,0,0,0};                // cols (lane&7)*8 + k
            #pragma unroll
            for (int i = 0; i < 8; ++i) {                   // row r = i*8 + (lane>>3)
                uint4 v = src[i * 64 + lane];
                unsigned uu[4] = {v.x, v.y, v.z, v.w};
                float rp = 0.f;
                #pragma unroll
                for (int k = 0; k < 4; ++k) {
                    float f0 = bf_lo(uu[k]), f1 = bf_hi(uu[k]);
                    rp += f0 + f1;
                    cp[2*k] += f0; cp[2*k+1] += f1;
                }
                rp += __shfl_xor(rp, 1, 64);                // 8 lanes share a row
                rp += __shfl_xor(rp, 2, 64);
                rp += __shfl_xor(rp, 4, 64);
                if ((lane & 7) == 0)
                    gh[(size_t)tile * 64 + i * 8 + (lane >> 3)] = rp * (1.f/64.f);
            }
            #pragma unroll
            for (int k = 0; k < 8; ++k) {                   // sum over row groups
                cp[k] += __shfl_xor(cp[k], 8, 64);
                cp[k] += __shfl_xor(cp[k], 16, 64);
                cp[k] += __shfl_xor(cp[k], 32, 64);
            }
            if (lane < 8) {                                 // lane holds cols lane*8..+7
                float4 a = make_float4(cp[0], cp[1], cp[2], cp[3]);
                float4 b = make_float4(cp[4], cp[5], cp[6], cp[7]);
                a.x *= (1.f/64.f); a.y *= (1.f/64.f); a.z *= (1.f/64.f); a.w *= (1.f/64.f);
                b.x *= (1.f/64.f); b.y *= (1.f/64.f); b.z *= (1.f/64.f); b.w *= (1.f/64.f);
                float4* dst = (float4*)(gw + (size_t)tile * 64 + lane * 8);
                dst[0] = a; dst[1] = b;
            }
        } else {
            const float4* src = (const float4*)((const float*)xv + (size_t)tile * 4096);
            float cp[4] = {0,0,0,0};                        // cols (lane&15)*4 + k
            #pragma unroll
            for (int i = 0; i < 16; ++i) {                  // row r = i*4 + (lane>>4)
                float4 v = src[i * 64 + lane];
                float rp = (v.x + v.y) + (v.z + v.w);
                cp[0] += v.x; cp[1] += v.y; cp[2] += v.z; cp[3] += v.w;
                rp += __shfl_xor(rp, 1, 64);                // 16 lanes share a row
                rp += __shfl_xor(rp, 2, 64);
                rp += __shfl_xor(rp, 4, 64);
                rp += __shfl_xor(rp, 8, 64);
                if ((lane & 15) == 0)
                    gh[(size_t)tile * 64 + i * 4 + (lane >> 4)] = rp * (1.f/64.f);
            }
            #pragma unroll
            for (int k = 0; k < 4; ++k) {
                cp[k] += __shfl_xor(cp[k], 16, 64);
                cp[k] += __shfl_xor(cp[k], 32, 64);
            }
            if (lane < 16) {                                // lane holds cols lane*4..+3
                float4 a = make_float4(cp[0] * (1.f/64.f), cp[1] * (1.f/64.f),
                                       cp[2] * (1.f/64.f), cp[3] * (1.f/64.f));
                *(float4*)(gw + (size_t)tile * 64 + lane * 4) = a;
            }
        }
    }
}

// ---------------------------------------------------------------------------
// K2: per (n,g): y = hswish(BN(W1@[gh|gw]+b1)) in LDS, then full attention
// maps A_h/A_w -> global.  grid = 64 blocks.  (unchanged, verified)
// ---------------------------------------------------------------------------
__global__ __launch_bounds__(256) void kmid(
    const void* __restrict__ xv,
    const float* __restrict__ gh, const float* __restrict__ gw,
    const void* __restrict__ W1, const void* __restrict__ b1,
    const void* __restrict__ gamma, const void* __restrict__ beta,
    const void* __restrict__ mean, const void* __restrict__ var,
    const void* __restrict__ Wh, const void* __restrict__ bh,
    const void* __restrict__ Ww, const void* __restrict__ bw,
    float* __restrict__ aH, float* __restrict__ aW)
{
    __shared__ float W1_s[MIP * CG];       // [m][cc]
    __shared__ float Whw_s[2][CG * MIP];   // [hf][cc][m]
    __shared__ float y_s[MIP * 128];       // [m][l]
    __shared__ float bhw_s[2][CG];
    __shared__ float scale_s[MIP], shift_s[MIP], b1_s[MIP];
    __shared__ unsigned flag_s;

    const int t = threadIdx.x;
    const int ng = blockIdx.x;             // n*4 + g
    const bool isbf = sniff_isbf((const unsigned*)xv, t, &flag_s);

    if (isbf) {
        uint4 v = ((const uint4*)W1)[t];   // 2048 bf16 = 256 uint4
        unsigned uu[4] = {v.x, v.y, v.z, v.w};
        #pragma unroll
        for (int k = 0; k < 4; ++k) {
            W1_s[t*8 + 2*k]   = bf_lo(uu[k]);
            W1_s[t*8 + 2*k+1] = bf_hi(uu[k]);
        }
        uint4 a = ((const uint4*)Wh)[t];
        unsigned ua[4] = {a.x, a.y, a.z, a.w};
        #pragma unroll
        for (int k = 0; k < 4; ++k) {
            Whw_s[0][t*8 + 2*k]   = bf_lo(ua[k]);
            Whw_s[0][t*8 + 2*k+1] = bf_hi(ua[k]);
        }
        uint4 c = ((const uint4*)Ww)[t];
        unsigned uc[4] = {c.x, c.y, c.z, c.w};
        #pragma unroll
        for (int k = 0; k < 4; ++k) {
            Whw_s[1][t*8 + 2*k]   = bf_lo(uc[k]);
            Whw_s[1][t*8 + 2*k+1] = bf_hi(uc[k]);
        }
    } else {
        #pragma unroll
        for (int it = 0; it < 2; ++it) {
            int idx = t + 256 * it;        // 2048 fp32 = 512 float4
            float4 v = ((const float4*)W1)[idx];
            W1_s[idx*4] = v.x; W1_s[idx*4+1] = v.y; W1_s[idx*4+2] = v.z; W1_s[idx*4+3] = v.w;
            float4 a = ((const float4*)Wh)[idx];
            Whw_s[0][idx*4] = a.x; Whw_s[0][idx*4+1] = a.y; Whw_s[0][idx*4+2] = a.z; Whw_s[0][idx*4+3] = a.w;
            float4 c = ((const float4*)Ww)[idx];
            Whw_s[1][idx*4] = c.x; Whw_s[1][idx*4+1] = c.y; Whw_s[1][idx*4+2] = c.z; Whw_s[1][idx*4+3] = c.w;
        }
    }
    if (t < CG) bhw_s[0][t] = ld_scalar(bh, t, isbf);
    else        bhw_s[1][t - CG] = ld_scalar(bw, t - CG, isbf);
    if (t < MIP) {
        float sc = ld_scalar(gamma, t, isbf) * rsqrtf(ld_scalar(var, t, isbf) + 1e-5f);
        scale_s[t] = sc;
        shift_s[t] = ld_scalar(beta, t, isbf) - ld_scalar(mean, t, isbf) * sc;
        b1_s[t] = ld_scalar(b1, t, isbf);
    }
    __syncthreads();

    {
        const int l = t & 127;
        const int half = t >> 7;
        const float* gbase = (l < 64) ? (gh + (size_t)ng * 8192 + l)
                                      : (gw + (size_t)ng * 8192 + (l - 64));
        float acc[8] = {0,0,0,0,0,0,0,0};
        for (int cc = 0; cc < CG; ++cc) {
            float v = gbase[(size_t)cc * 64];
            #pragma unroll
            for (int mm = 0; mm < 8; ++mm)
                acc[mm] += W1_s[(half*8 + mm) * CG + cc] * v;
        }
        #pragma unroll
        for (int mm = 0; mm < 8; ++mm) {
            int m = half*8 + mm;
            float yv = acc[mm] + b1_s[m];
            yv = yv * scale_s[m] + shift_s[m];
            float hc = fminf(fmaxf(yv + 3.f, 0.f), 6.f);
            y_s[m * 128 + l] = yv * hc * (1.f/6.f);
        }
    }
    __syncthreads();

    for (int k = 0; k < 64; ++k) {
        int out = t + 256 * k;             // wave-uniform (hf,cc), i = lane
        int hf = out >> 13;
        int rem = out & 8191;
        int cc = rem >> 6;
        int i = rem & 63;
        float acc = bhw_s[hf][cc];
        #pragma unroll
        for (int m = 0; m < MIP; ++m)
            acc += Whw_s[hf][cc * MIP + m] * y_s[m * 128 + hf * 64 + i];
        float s = 1.f / (1.f + __expf(-acc));
        float* dst = hf ? aW : aH;
        dst[(size_t)ng * 8192 + cc * 64 + i] = s;
    }
}

// ---------------------------------------------------------------------------
// K3: wave-autonomous streaming gate. 1024 blocks x 4 waves x 2 tiles = 8192.
// Zero LDS, zero barriers. Per tile: 2 coalesced A-row loads; aw col-block is
// iter-invariant per lane -> hoisted via shuffles once; ah[r] = 1 shfl/iter.
// ---------------------------------------------------------------------------
__global__ __launch_bounds__(256) void kapply(const void* __restrict__ xv,
                                              const float* __restrict__ aH,
                                              const float* __restrict__ aW,
                                              void* __restrict__ outv) {
    const int lane = threadIdx.x & 63;
    const int gwid = blockIdx.x * 4 + (threadIdx.x >> 6);   // 0..4095
    const bool isbf = wave_sniff_isbf((const unsigned*)xv, lane);

    #pragma unroll
    for (int j = 0; j < 2; ++j) {
        const int bid = gwid * 2 + j;          // n*512 + o
        const int n = bid >> 9;
        const int o = bid & 511;
        const int p = (o & 127) * 4 + (o >> 7);    // channel shuffle
        const int g = p >> 7, cc = p & 127;
        const size_t abase = (size_t)(n * 4 + g) * 8192 + (size_t)cc * 64;

        const float ah_r = aH[abase + lane];   // coalesced 256 B
        const float aw_r = aW[abase + lane];

        if (isbf) {
            float awv[8];
            #pragma unroll
            for (int k = 0; k < 8; ++k)
                awv[k] = __shfl(aw_r, (lane & 7) * 8 + k, 64);  // iter-invariant
            const uint4* src = (const uint4*)((const unsigned short*)xv + ((size_t)n * 512 + p) * 4096);
            uint4* dst = (uint4*)((unsigned short*)outv + (size_t)bid * 4096);
            #pragma unroll
            for (int i = 0; i < 8; ++i) {
                float sah = __shfl(ah_r, i * 8 + (lane >> 3), 64);
                uint4 v = src[i * 64 + lane];
                unsigned uu[4] = {v.x, v.y, v.z, v.w};
                unsigned res[4];
                #pragma unroll
                for (int k = 0; k < 4; ++k) {
                    float f0 = bf_lo(uu[k]) * sah * awv[2*k];
                    float f1 = bf_hi(uu[k]) * sah * awv[2*k+1];
                    unsigned u0 = __float_as_uint(f0); u0 += 0x7FFFu + ((u0 >> 16) & 1u);
                    unsigned u1 = __float_as_uint(f1); u1 += 0x7FFFu + ((u1 >> 16) & 1u);
                    res[k] = (u0 >> 16) | (u1 & 0xFFFF0000u);
                }
                uint4 w2; w2.x = res[0]; w2.y = res[1]; w2.z = res[2]; w2.w = res[3];
                dst[i * 64 + lane] = w2;
            }
        } else {
            float awv[4];
            #pragma unroll
            for (int k = 0; k < 4; ++k)
                awv[k] = __shfl(aw_r, (lane & 15) * 4 + k, 64);
            const float4* src = (const float4*)((const float*)xv + ((size_t)n * 512 + p) * 4096);
            float4* dst = (float4*)((float*)outv + (size_t)bid * 4096);
            #pragma unroll
            for (int i = 0; i < 16; ++i) {
                float sah = __shfl(ah_r, i * 4 + (lane >> 4), 64);
                float4 v = src[i * 64 + lane];
                v.x *= sah * awv[0];
                v.y *= sah * awv[1];
                v.z *= sah * awv[2];
                v.w *= sah * awv[3];
                dst[i * 64 + lane] = v;
            }
        }
    }
}

extern "C" void kernel_launch(void* const* d_in, const int* in_sizes, int n_in,
                              void* d_out, int out_size, void* d_ws, size_t ws_size,
                              hipStream_t stream) {
    const void* x     = d_in[0];
    const void* W1    = d_in[1];
    const void* b1    = d_in[2];
    const void* gamma = d_in[3];
    const void* beta  = d_in[4];
    const void* mean  = d_in[5];
    const void* var   = d_in[6];
    const void* Wh    = d_in[7];
    const void* bh    = d_in[8];
    const void* Ww    = d_in[9];
    const void* bw    = d_in[10];

    float* ws = (float*)d_ws;
    float* gh = ws;                    // 524288 floats (2 MB)
    float* gw = gh + 524288;           // 524288 floats
    float* aH = gw + 524288;           // 524288 floats
    float* aW = aH + 524288;           // 524288 floats

    kreduce<<<1024, 256, 0, stream>>>(x, gh, gw);
    kmid<<<N_ * GRP, 256, 0, stream>>>(x, gh, gw, W1, b1, gamma, beta, mean, var,
                                       Wh, bh, Ww, bw, aH, aW);
    kapply<<<1024, 256, 0, stream>>>(x, aH, aW, d_out);
}

// Round 6
// 286.406 us; speedup vs baseline: 1.8860x; 1.0310x over previous
//
#include <hip/hip_runtime.h>

#define N_   16
#define C_   512
#define GRP  4
#define CG   128
#define MIP  16

__device__ __forceinline__ float bf_lo(unsigned u) { return __uint_as_float(u << 16); }
__device__ __forceinline__ float bf_hi(unsigned u) { return __uint_as_float(u & 0xFFFF0000u); }
__device__ __forceinline__ float bf1(unsigned short s) { return __uint_as_float((unsigned)s << 16); }

__device__ __forceinline__ float ld_scalar(const void* p, int i, bool isbf) {
    return isbf ? bf1(((const unsigned short*)p)[i]) : ((const float*)p)[i];
}

// Wave-level dtype sniff: no LDS, no barrier. Reads x[0..255] words (L2-hot).
__device__ __forceinline__ bool wave_sniff_isbf(const unsigned* __restrict__ x32,
                                                int lane) {
    int cnt = 0;
    #pragma unroll
    for (int k = 0; k < 4; ++k) {
        unsigned w = x32[lane + 64 * k];
        unsigned e = (w >> 7) & 0xFFu;
        cnt += (e >= 0x60u && e <= 0x9Fu) ? 1 : 0;
    }
    #pragma unroll
    for (int off = 32; off > 0; off >>= 1) cnt += __shfl_xor(cnt, off, 64);
    return cnt >= 192;
}

// Block-level sniff (ky only).
__device__ __forceinline__ bool sniff_isbf(const unsigned* __restrict__ x32,
                                           int t, unsigned* s_flag) {
    if (t < 64) {
        int cnt = 0;
        #pragma unroll
        for (int k = 0; k < 4; ++k) {
            unsigned w = x32[t + 64 * k];
            unsigned e = (w >> 7) & 0xFFu;
            cnt += (e >= 0x60u && e <= 0x9Fu) ? 1 : 0;
        }
        #pragma unroll
        for (int off = 32; off > 0; off >>= 1) cnt += __shfl_down(cnt, off, 64);
        if (t == 0) *s_flag = (cnt >= 192) ? 1u : 0u;
    }
    __syncthreads();
    return *s_flag != 0u;
}

// ---------------------------------------------------------------------------
// K1: wave-autonomous tile reduce. 2048 blocks x 4 waves x 1 tile = 8192.
// Zero LDS, zero barriers (verified internals from round 5).
// ---------------------------------------------------------------------------
__global__ __launch_bounds__(256) void kreduce(const void* __restrict__ xv,
                                               float* __restrict__ gh,
                                               float* __restrict__ gw) {
    const int lane = threadIdx.x & 63;
    const int tile = blockIdx.x * 4 + (threadIdx.x >> 6);   // 0..8191 = n*512+ch
    const bool isbf = wave_sniff_isbf((const unsigned*)xv, lane);

    if (isbf) {
        const uint4* src = (const uint4*)((const unsigned short*)xv + (size_t)tile * 4096);
        float cp[8] = {0,0,0,0,0,0,0,0};                // cols (lane&7)*8 + k
        #pragma unroll
        for (int i = 0; i < 8; ++i) {                   // row r = i*8 + (lane>>3)
            uint4 v = src[i * 64 + lane];
            unsigned uu[4] = {v.x, v.y, v.z, v.w};
            float rp = 0.f;
            #pragma unroll
            for (int k = 0; k < 4; ++k) {
                float f0 = bf_lo(uu[k]), f1 = bf_hi(uu[k]);
                rp += f0 + f1;
                cp[2*k] += f0; cp[2*k+1] += f1;
            }
            rp += __shfl_xor(rp, 1, 64);                // 8 lanes share a row
            rp += __shfl_xor(rp, 2, 64);
            rp += __shfl_xor(rp, 4, 64);
            if ((lane & 7) == 0)
                gh[(size_t)tile * 64 + i * 8 + (lane >> 3)] = rp * (1.f/64.f);
        }
        #pragma unroll
        for (int k = 0; k < 8; ++k) {                   // sum over row groups
            cp[k] += __shfl_xor(cp[k], 8, 64);
            cp[k] += __shfl_xor(cp[k], 16, 64);
            cp[k] += __shfl_xor(cp[k], 32, 64);
        }
        if (lane < 8) {                                 // lane holds cols lane*8..+7
            float4 a = make_float4(cp[0]*(1.f/64.f), cp[1]*(1.f/64.f),
                                   cp[2]*(1.f/64.f), cp[3]*(1.f/64.f));
            float4 b = make_float4(cp[4]*(1.f/64.f), cp[5]*(1.f/64.f),
                                   cp[6]*(1.f/64.f), cp[7]*(1.f/64.f));
            float4* dst = (float4*)(gw + (size_t)tile * 64 + lane * 8);
            dst[0] = a; dst[1] = b;
        }
    } else {
        const float4* src = (const float4*)((const float*)xv + (size_t)tile * 4096);
        float cp[4] = {0,0,0,0};                        // cols (lane&15)*4 + k
        #pragma unroll
        for (int i = 0; i < 16; ++i) {                  // row r = i*4 + (lane>>4)
            float4 v = src[i * 64 + lane];
            float rp = (v.x + v.y) + (v.z + v.w);
            cp[0] += v.x; cp[1] += v.y; cp[2] += v.z; cp[3] += v.w;
            rp += __shfl_xor(rp, 1, 64);                // 16 lanes share a row
            rp += __shfl_xor(rp, 2, 64);
            rp += __shfl_xor(rp, 4, 64);
            rp += __shfl_xor(rp, 8, 64);
            if ((lane & 15) == 0)
                gh[(size_t)tile * 64 + i * 4 + (lane >> 4)] = rp * (1.f/64.f);
        }
        #pragma unroll
        for (int k = 0; k < 4; ++k) {
            cp[k] += __shfl_xor(cp[k], 16, 64);
            cp[k] += __shfl_xor(cp[k], 32, 64);
        }
        if (lane < 16) {                                // lane holds cols lane*4..+3
            float4 a = make_float4(cp[0]*(1.f/64.f), cp[1]*(1.f/64.f),
                                   cp[2]*(1.f/64.f), cp[3]*(1.f/64.f));
            *(float4*)(gw + (size_t)tile * 64 + lane * 4) = a;
        }
    }
}

// ---------------------------------------------------------------------------
// K2: per (n,g): y = hardswish(BN(W1 @ [gh|gw] + b1)) -> y[ng][16][128] fp32
// grid = 64 blocks, 256 threads. (verified in round 0; y = 512 KB, L3-hot)
// ---------------------------------------------------------------------------
__global__ __launch_bounds__(256) void ky(
    const void* __restrict__ xv,
    const float* __restrict__ gh, const float* __restrict__ gw,
    const void* __restrict__ W1, const void* __restrict__ b1,
    const void* __restrict__ gamma, const void* __restrict__ beta,
    const void* __restrict__ mean, const void* __restrict__ var,
    float* __restrict__ y)
{
    __shared__ float W1_s[MIP * CG];   // [m][cc]
    __shared__ float scale_s[MIP], shift_s[MIP], b1_s[MIP];
    __shared__ unsigned flag_s;

    const int t = threadIdx.x;
    const bool isbf = sniff_isbf((const unsigned*)xv, t, &flag_s);

    if (isbf) {
        uint4 v = ((const uint4*)W1)[t];
        unsigned uu[4] = {v.x, v.y, v.z, v.w};
        #pragma unroll
        for (int k = 0; k < 4; ++k) {
            W1_s[t * 8 + 2 * k]     = bf_lo(uu[k]);
            W1_s[t * 8 + 2 * k + 1] = bf_hi(uu[k]);
        }
    } else {
        #pragma unroll
        for (int it = 0; it < 2; ++it) {
            int idx = t + 256 * it;
            float4 v = ((const float4*)W1)[idx];
            W1_s[idx * 4]     = v.x;
            W1_s[idx * 4 + 1] = v.y;
            W1_s[idx * 4 + 2] = v.z;
            W1_s[idx * 4 + 3] = v.w;
        }
    }
    if (t < MIP) {
        float sc = ld_scalar(gamma, t, isbf) * rsqrtf(ld_scalar(var, t, isbf) + 1e-5f);
        scale_s[t] = sc;
        shift_s[t] = ld_scalar(beta, t, isbf) - ld_scalar(mean, t, isbf) * sc;
        b1_s[t] = ld_scalar(b1, t, isbf);
    }
    __syncthreads();

    const int l = t & 127;
    const int half = t >> 7;
    const size_t base = (size_t)blockIdx.x * (CG * 64);
    const float* src = (l < 64) ? (gh + base + l) : (gw + base + (l - 64));
    float acc[8] = {0.f, 0.f, 0.f, 0.f, 0.f, 0.f, 0.f, 0.f};
    for (int cc = 0; cc < CG; ++cc) {
        float v = src[(size_t)cc * 64];
        #pragma unroll
        for (int mm = 0; mm < 8; ++mm)
            acc[mm] += W1_s[(half * 8 + mm) * CG + cc] * v;
    }
    float* yb = y + (size_t)blockIdx.x * (MIP * 128);
    #pragma unroll
    for (int mm = 0; mm < 8; ++mm) {
        int m = half * 8 + mm;
        float yv = acc[mm] + b1_s[m];
        yv = yv * scale_s[m] + shift_s[m];
        float hc = fminf(fmaxf(yv + 3.0f, 0.0f), 6.0f);
        yb[m * 128 + l] = yv * hc * (1.0f / 6.0f);
    }
}

// ---------------------------------------------------------------------------
// K3: wave-autonomous gate. 2048 blocks x 4 waves x 1 tile = 8192 channels.
// Per wave: in-register GEMV head (lane i computes a_h[i], a_w[i] directly:
// 32 coalesced y-loads + broadcast W-loads, all 64 lanes busy, no LDS, no
// barriers), then shuffle-distributed streaming gate.
// ---------------------------------------------------------------------------
__global__ __launch_bounds__(256) void kapply(const void* __restrict__ xv,
                                              const float* __restrict__ y,
                                              const void* __restrict__ Wh,
                                              const void* __restrict__ bh,
                                              const void* __restrict__ Ww,
                                              const void* __restrict__ bw,
                                              void* __restrict__ outv) {
    const int lane = threadIdx.x & 63;
    const int bid = blockIdx.x * 4 + (threadIdx.x >> 6);   // n*512 + o
    const bool isbf = wave_sniff_isbf((const unsigned*)xv, lane);

    const int n = bid >> 9;
    const int o = bid & 511;
    const int p = (o & 127) * 4 + (o >> 7);    // channel shuffle: input channel
    const int g = p >> 7, cc = p & 127;

    // ---- GEMV head: a_h[lane], a_w[lane] in registers ----
    const float* ysrc = y + (size_t)(n * 4 + g) * (MIP * 128);
    float acch = ld_scalar(bh, cc, isbf);
    float accw = ld_scalar(bw, cc, isbf);
    #pragma unroll
    for (int m = 0; m < MIP; ++m) {
        float wh = ld_scalar(Wh, cc * MIP + m, isbf);   // wave-uniform broadcast
        float ww = ld_scalar(Ww, cc * MIP + m, isbf);
        acch += wh * ysrc[m * 128 + lane];              // coalesced 256 B
        accw += ww * ysrc[m * 128 + 64 + lane];
    }
    const float ah_r = 1.0f / (1.0f + __expf(-acch));
    const float aw_r = 1.0f / (1.0f + __expf(-accw));

    // ---- streaming gate ----
    if (isbf) {
        float awv[8];
        #pragma unroll
        for (int k = 0; k < 8; ++k)
            awv[k] = __shfl(aw_r, (lane & 7) * 8 + k, 64);  // iter-invariant cols
        const uint4* src = (const uint4*)((const unsigned short*)xv + ((size_t)n * 512 + p) * 4096);
        uint4* dst = (uint4*)((unsigned short*)outv + (size_t)bid * 4096);
        #pragma unroll
        for (int i = 0; i < 8; ++i) {
            float sah = __shfl(ah_r, i * 8 + (lane >> 3), 64);
            uint4 v = src[i * 64 + lane];
            unsigned uu[4] = {v.x, v.y, v.z, v.w};
            unsigned res[4];
            #pragma unroll
            for (int k = 0; k < 4; ++k) {
                float f0 = bf_lo(uu[k]) * sah * awv[2*k];
                float f1 = bf_hi(uu[k]) * sah * awv[2*k+1];
                unsigned u0 = __float_as_uint(f0); u0 += 0x7FFFu + ((u0 >> 16) & 1u);
                unsigned u1 = __float_as_uint(f1); u1 += 0x7FFFu + ((u1 >> 16) & 1u);
                res[k] = (u0 >> 16) | (u1 & 0xFFFF0000u);
            }
            uint4 w2; w2.x = res[0]; w2.y = res[1]; w2.z = res[2]; w2.w = res[3];
            dst[i * 64 + lane] = w2;
        }
    } else {
        float awv[4];
        #pragma unroll
        for (int k = 0; k < 4; ++k)
            awv[k] = __shfl(aw_r, (lane & 15) * 4 + k, 64);
        const float4* src = (const float4*)((const float*)xv + ((size_t)n * 512 + p) * 4096);
        float4* dst = (float4*)((float*)outv + (size_t)bid * 4096);
        #pragma unroll
        for (int i = 0; i < 16; ++i) {
            float sah = __shfl(ah_r, i * 4 + (lane >> 4), 64);
            float4 v = src[i * 64 + lane];
            v.x *= sah * awv[0];
            v.y *= sah * awv[1];
            v.z *= sah * awv[2];
            v.w *= sah * awv[3];
            dst[i * 64 + lane] = v;
        }
    }
}

extern "C" void kernel_launch(void* const* d_in, const int* in_sizes, int n_in,
                              void* d_out, int out_size, void* d_ws, size_t ws_size,
                              hipStream_t stream) {
    const void* x     = d_in[0];
    const void* W1    = d_in[1];
    const void* b1    = d_in[2];
    const void* gamma = d_in[3];
    const void* beta  = d_in[4];
    const void* mean  = d_in[5];
    const void* var   = d_in[6];
    const void* Wh    = d_in[7];
    const void* bh    = d_in[8];
    const void* Ww    = d_in[9];
    const void* bw    = d_in[10];

    float* ws = (float*)d_ws;
    float* gh = ws;                    // 524288 floats (2 MB)
    float* gw = gh + 524288;           // 524288 floats
    float* yv = gw + 524288;           // 131072 floats (512 KB)

    kreduce<<<2048, 256, 0, stream>>>(x, gh, gw);
    ky<<<N_ * GRP, 256, 0, stream>>>(x, gh, gw, W1, b1, gamma, beta, mean, var, yv);
    kapply<<<2048, 256, 0, stream>>>(x, yv, Wh, bh, Ww, bw, d_out);
}

// Round 7
// 286.330 us; speedup vs baseline: 1.8865x; 1.0003x over previous
//
#include <hip/hip_runtime.h>

#define N_   16
#define C_   512
#define GRP  4
#define CG   128
#define MIP  16

__device__ __forceinline__ float bf_lo(unsigned u) { return __uint_as_float(u << 16); }
__device__ __forceinline__ float bf_hi(unsigned u) { return __uint_as_float(u & 0xFFFF0000u); }
__device__ __forceinline__ float bf1(unsigned short s) { return __uint_as_float((unsigned)s << 16); }

__device__ __forceinline__ float ld_scalar(const void* p, int i, bool isbf) {
    return isbf ? bf1(((const unsigned short*)p)[i]) : ((const float*)p)[i];
}

// Wave-level dtype sniff: no LDS, no barrier. Reads x[0..255] words (L2-hot).
__device__ __forceinline__ bool wave_sniff_isbf(const unsigned* __restrict__ x32,
                                                int lane) {
    int cnt = 0;
    #pragma unroll
    for (int k = 0; k < 4; ++k) {
        unsigned w = x32[lane + 64 * k];
        unsigned e = (w >> 7) & 0xFFu;
        cnt += (e >= 0x60u && e <= 0x9Fu) ? 1 : 0;
    }
    #pragma unroll
    for (int off = 32; off > 0; off >>= 1) cnt += __shfl_xor(cnt, off, 64);
    return cnt >= 192;
}

// ---------------------------------------------------------------------------
// K1: wave-autonomous tile reduce. 2048 blocks x 4 waves x 1 tile = 8192.
// Zero LDS, zero barriers (verified in rounds 5/6).
// ---------------------------------------------------------------------------
__global__ __launch_bounds__(256) void kreduce(const void* __restrict__ xv,
                                               float* __restrict__ gh,
                                               float* __restrict__ gw) {
    const int lane = threadIdx.x & 63;
    const int tile = blockIdx.x * 4 + (threadIdx.x >> 6);   // 0..8191 = n*512+ch
    const bool isbf = wave_sniff_isbf((const unsigned*)xv, lane);

    if (isbf) {
        const uint4* src = (const uint4*)((const unsigned short*)xv + (size_t)tile * 4096);
        float cp[8] = {0,0,0,0,0,0,0,0};                // cols (lane&7)*8 + k
        #pragma unroll
        for (int i = 0; i < 8; ++i) {                   // row r = i*8 + (lane>>3)
            uint4 v = src[i * 64 + lane];
            unsigned uu[4] = {v.x, v.y, v.z, v.w};
            float rp = 0.f;
            #pragma unroll
            for (int k = 0; k < 4; ++k) {
                float f0 = bf_lo(uu[k]), f1 = bf_hi(uu[k]);
                rp += f0 + f1;
                cp[2*k] += f0; cp[2*k+1] += f1;
            }
            rp += __shfl_xor(rp, 1, 64);                // 8 lanes share a row
            rp += __shfl_xor(rp, 2, 64);
            rp += __shfl_xor(rp, 4, 64);
            if ((lane & 7) == 0)
                gh[(size_t)tile * 64 + i * 8 + (lane >> 3)] = rp * (1.f/64.f);
        }
        #pragma unroll
        for (int k = 0; k < 8; ++k) {                   // sum over row groups
            cp[k] += __shfl_xor(cp[k], 8, 64);
            cp[k] += __shfl_xor(cp[k], 16, 64);
            cp[k] += __shfl_xor(cp[k], 32, 64);
        }
        if (lane < 8) {                                 // lane holds cols lane*8..+7
            float4 a = make_float4(cp[0]*(1.f/64.f), cp[1]*(1.f/64.f),
                                   cp[2]*(1.f/64.f), cp[3]*(1.f/64.f));
            float4 b = make_float4(cp[4]*(1.f/64.f), cp[5]*(1.f/64.f),
                                   cp[6]*(1.f/64.f), cp[7]*(1.f/64.f));
            float4* dst = (float4*)(gw + (size_t)tile * 64 + lane * 8);
            dst[0] = a; dst[1] = b;
        }
    } else {
        const float4* src = (const float4*)((const float*)xv + (size_t)tile * 4096);
        float cp[4] = {0,0,0,0};                        // cols (lane&15)*4 + k
        #pragma unroll
        for (int i = 0; i < 16; ++i) {                  // row r = i*4 + (lane>>4)
            float4 v = src[i * 64 + lane];
            float rp = (v.x + v.y) + (v.z + v.w);
            cp[0] += v.x; cp[1] += v.y; cp[2] += v.z; cp[3] += v.w;
            rp += __shfl_xor(rp, 1, 64);                // 16 lanes share a row
            rp += __shfl_xor(rp, 2, 64);
            rp += __shfl_xor(rp, 4, 64);
            rp += __shfl_xor(rp, 8, 64);
            if ((lane & 15) == 0)
                gh[(size_t)tile * 64 + i * 4 + (lane >> 4)] = rp * (1.f/64.f);
        }
        #pragma unroll
        for (int k = 0; k < 4; ++k) {
            cp[k] += __shfl_xor(cp[k], 16, 64);
            cp[k] += __shfl_xor(cp[k], 32, 64);
        }
        if (lane < 16) {                                // lane holds cols lane*4..+3
            float4 a = make_float4(cp[0]*(1.f/64.f), cp[1]*(1.f/64.f),
                                   cp[2]*(1.f/64.f), cp[3]*(1.f/64.f));
            *(float4*)(gw + (size_t)tile * 64 + lane * 4) = a;
        }
    }
}

// ---------------------------------------------------------------------------
// K2: fused y + gate. 1024 blocks x 256 threads; block b owns output
// channels bid = 8b..8b+7. The channel shuffle p=(o&127)*4+(o>>7) keeps
// (n,g) block-invariant (proof: ((8b&127)+j)*4+g2 mod 128 <= 127, never
// crosses a group boundary), so the block computes its group's y[16][128]
// ONCE into LDS (ky's verified math), then each wave runs the verified
// in-register GEMV head + shuffle-gate for 2 channels. Deletes the ky
// dispatch and the y global round-trip.
// ---------------------------------------------------------------------------
__global__ __launch_bounds__(256) void kfused(
    const void* __restrict__ xv,
    const float* __restrict__ gh, const float* __restrict__ gw,
    const void* __restrict__ W1, const void* __restrict__ b1,
    const void* __restrict__ gamma, const void* __restrict__ beta,
    const void* __restrict__ mean, const void* __restrict__ var,
    const void* __restrict__ Wh, const void* __restrict__ bh,
    const void* __restrict__ Ww, const void* __restrict__ bw,
    void* __restrict__ outv)
{
    __shared__ float W1_s[MIP * CG];   // [m][cc]
    __shared__ float y_s[MIP * 128];   // [m][l]
    __shared__ float scale_s[MIP], shift_s[MIP], b1_s[MIP];

    const int t = threadIdx.x;
    const int lane = t & 63;
    const int wv = t >> 6;
    const int b = blockIdx.x;                  // 0..1023
    const bool isbf = wave_sniff_isbf((const unsigned*)xv, lane);

    // ---- stage W1 + BN params (ky's verified staging) ----
    if (isbf) {
        uint4 v = ((const uint4*)W1)[t];
        unsigned uu[4] = {v.x, v.y, v.z, v.w};
        #pragma unroll
        for (int k = 0; k < 4; ++k) {
            W1_s[t * 8 + 2 * k]     = bf_lo(uu[k]);
            W1_s[t * 8 + 2 * k + 1] = bf_hi(uu[k]);
        }
    } else {
        #pragma unroll
        for (int it = 0; it < 2; ++it) {
            int idx = t + 256 * it;
            float4 v = ((const float4*)W1)[idx];
            W1_s[idx * 4]     = v.x;
            W1_s[idx * 4 + 1] = v.y;
            W1_s[idx * 4 + 2] = v.z;
            W1_s[idx * 4 + 3] = v.w;
        }
    }
    if (t < MIP) {
        float sc = ld_scalar(gamma, t, isbf) * rsqrtf(ld_scalar(var, t, isbf) + 1e-5f);
        scale_s[t] = sc;
        shift_s[t] = ld_scalar(beta, t, isbf) - ld_scalar(mean, t, isbf) * sc;
        b1_s[t] = ld_scalar(b1, t, isbf);
    }
    __syncthreads();

    // ---- block-invariant (n, g) ----
    const int n  = b >> 6;                     // (8b)>>9
    const int o0 = (8 * b) & 511;
    const int p0 = (o0 & 127) * 4 + (o0 >> 7);
    const int g  = p0 >> 7;
    const size_t base = (size_t)(n * 4 + g) * 8192;

    // ---- y phase (ky's verified math), result in LDS ----
    {
        const int l = t & 127;
        const int half = t >> 7;
        const float* src = (l < 64) ? (gh + base + l) : (gw + base + (l - 64));
        float acc[8] = {0.f, 0.f, 0.f, 0.f, 0.f, 0.f, 0.f, 0.f};
        for (int cc = 0; cc < CG; ++cc) {
            float v = src[(size_t)cc * 64];
            #pragma unroll
            for (int mm = 0; mm < 8; ++mm)
                acc[mm] += W1_s[(half * 8 + mm) * CG + cc] * v;
        }
        #pragma unroll
        for (int mm = 0; mm < 8; ++mm) {
            int m = half * 8 + mm;
            float yv = acc[mm] + b1_s[m];
            yv = yv * scale_s[m] + shift_s[m];
            float hc = fminf(fmaxf(yv + 3.0f, 0.0f), 6.0f);
            y_s[m * 128 + l] = yv * hc * (1.0f / 6.0f);
        }
    }
    __syncthreads();

    // ---- per-wave: 2 output channels ----
    #pragma unroll
    for (int j = 0; j < 2; ++j) {
        const int bid = 8 * b + wv * 2 + j;    // n*512 + o
        const int o = bid & 511;
        const int p = (o & 127) * 4 + (o >> 7);
        const int cc = p & 127;

        // GEMV head: a_h[lane], a_w[lane] in registers (y from LDS)
        float acch = ld_scalar(bh, cc, isbf);
        float accw = ld_scalar(bw, cc, isbf);
        #pragma unroll
        for (int m = 0; m < MIP; ++m) {
            float wh = ld_scalar(Wh, cc * MIP + m, isbf);   // wave-uniform
            float ww = ld_scalar(Ww, cc * MIP + m, isbf);
            acch += wh * y_s[m * 128 + lane];               // conflict-free LDS
            accw += ww * y_s[m * 128 + 64 + lane];
        }
        const float ah_r = 1.0f / (1.0f + __expf(-acch));
        const float aw_r = 1.0f / (1.0f + __expf(-accw));

        // streaming gate (verified in rounds 5/6)
        if (isbf) {
            float awv[8];
            #pragma unroll
            for (int k = 0; k < 8; ++k)
                awv[k] = __shfl(aw_r, (lane & 7) * 8 + k, 64);
            const uint4* src = (const uint4*)((const unsigned short*)xv + ((size_t)n * 512 + p) * 4096);
            uint4* dst = (uint4*)((unsigned short*)outv + (size_t)bid * 4096);
            #pragma unroll
            for (int i = 0; i < 8; ++i) {
                float sah = __shfl(ah_r, i * 8 + (lane >> 3), 64);
                uint4 v = src[i * 64 + lane];
                unsigned uu[4] = {v.x, v.y, v.z, v.w};
                unsigned res[4];
                #pragma unroll
                for (int k = 0; k < 4; ++k) {
                    float f0 = bf_lo(uu[k]) * sah * awv[2*k];
                    float f1 = bf_hi(uu[k]) * sah * awv[2*k+1];
                    unsigned u0 = __float_as_uint(f0); u0 += 0x7FFFu + ((u0 >> 16) & 1u);
                    unsigned u1 = __float_as_uint(f1); u1 += 0x7FFFu + ((u1 >> 16) & 1u);
                    res[k] = (u0 >> 16) | (u1 & 0xFFFF0000u);
                }
                uint4 w2; w2.x = res[0]; w2.y = res[1]; w2.z = res[2]; w2.w = res[3];
                dst[i * 64 + lane] = w2;
            }
        } else {
            float awv[4];
            #pragma unroll
            for (int k = 0; k < 4; ++k)
                awv[k] = __shfl(aw_r, (lane & 15) * 4 + k, 64);
            const float4* src = (const float4*)((const float*)xv + ((size_t)n * 512 + p) * 4096);
            float4* dst = (float4*)((float*)outv + (size_t)bid * 4096);
            #pragma unroll
            for (int i = 0; i < 16; ++i) {
                float sah = __shfl(ah_r, i * 4 + (lane >> 4), 64);
                float4 v = src[i * 64 + lane];
                v.x *= sah * awv[0];
                v.y *= sah * awv[1];
                v.z *= sah * awv[2];
                v.w *= sah * awv[3];
                dst[i * 64 + lane] = v;
            }
        }
    }
}

extern "C" void kernel_launch(void* const* d_in, const int* in_sizes, int n_in,
                              void* d_out, int out_size, void* d_ws, size_t ws_size,
                              hipStream_t stream) {
    const void* x     = d_in[0];
    const void* W1    = d_in[1];
    const void* b1    = d_in[2];
    const void* gamma = d_in[3];
    const void* beta  = d_in[4];
    const void* mean  = d_in[5];
    const void* var   = d_in[6];
    const void* Wh    = d_in[7];
    const void* bh    = d_in[8];
    const void* Ww    = d_in[9];
    const void* bw    = d_in[10];

    float* ws = (float*)d_ws;
    float* gh = ws;                    // 524288 floats (2 MB)
    float* gw = gh + 524288;           // 524288 floats

    kreduce<<<2048, 256, 0, stream>>>(x, gh, gw);
    kfused<<<1024, 256, 0, stream>>>(x, gh, gw, W1, b1, gamma, beta, mean, var,
                                     Wh, bh, Ww, bw, d_out);
}